// Round 3
// baseline (2209.556 us; speedup 1.0000x reference)
//
#include <hip/hip_runtime.h>

typedef _Float16 f16;
typedef _Float16 half8 __attribute__((ext_vector_type(8)));
typedef float f32x4 __attribute__((ext_vector_type(4)));
typedef unsigned long long u64;

#define B_  64
#define T_  512
#define V_  32000
#define E_  300
#define EP  320      // E padded to multiple of 32 for MFMA K
#define U_  1024
#define G3  3072     // 3*U

// ---- workspace layout (bytes) ----
// XE region is time-shared: k_gather/k_xp use it first, then hx/ctr live in it.
#define OFF_XE   0ull
#define OFF_HX   OFF_XE                               // hx[2][64][1024] fp16 (256 KB)
#define OFF_CTR2 (OFF_XE + 2ull*B_*U_*2)              // ctr[4][2048] (32 KB)
#define OFF_W1T  (OFF_XE  + (size_t)B_*T_*EP*2)       // xe fp16 [32768][320]
#define OFF_W2F  (OFF_W1T + (size_t)G3*EP*2)
#define OFF_XP   (OFF_W2F + (size_t)U_*G3*2)

__device__ __forceinline__ void barrier_lds() {
    // LDS-only dependency barrier: don't drain vmcnt (keeps prefetches alive)
    asm volatile("s_waitcnt lgkmcnt(0)\n\ts_barrier" ::: "memory");
}

// opaque 16B load: result is an asm output -> cannot be rematerialized, so
// the allocator must keep it in VGPRs for its whole live range
#define WLOAD(dst, src) \
    asm volatile("global_load_dwordx4 %0, %1, off" : "=v"(dst) : "v"(src) : "memory")
// L1/L2-bypassing 16B load (coherent at L3; producers drained theirs pre-barrier)
#define CLOAD(dst, src) \
    asm volatile("global_load_dwordx4 %0, %1, off sc0 sc1" : "=v"(dst) : "v"(src) : "memory")
// same, with a literal byte offset (string)
#define CLOADO(dst, src, imm) \
    asm volatile("global_load_dwordx4 %0, %1, off offset:" imm " sc0 sc1" \
                 : "=v"(dst) : "v"(src) : "memory")
// vmcnt drain whose protected values feed REGISTER-ONLY consumers (MFMA):
// needs sched_barrier(0) or hipcc hoists the consumer past the waitcnt
// (rule #18 — "memory" clobber doesn't order non-memory instructions).
#define VMFENCE() do {                                      \
    asm volatile("s_waitcnt vmcnt(0)" ::: "memory");        \
    __builtin_amdgcn_sched_barrier(0);                      \
} while (0)

// ---------------- setup kernels ----------------

__global__ void k_gather(const int* __restrict__ x, const float* __restrict__ emb,
                         f16* __restrict__ xe) {
    int row  = blockIdx.x * 4 + (threadIdx.x >> 6);
    int lane = threadIdx.x & 63;
    int tok  = x[row];
    const float* er = emb + (size_t)tok * E_;
    f16* xr = xe + (size_t)row * EP;
#pragma unroll
    for (int e = lane; e < EP; e += 64) {
        float v = (e < E_) ? er[e] : 0.f;
        xr[e] = (f16)v;
    }
}

__global__ void k_w1t(const float* __restrict__ w1, f16* __restrict__ w1t) {
    int n = blockIdx.x;
    int k = threadIdx.x;
    float v = (k < E_) ? w1[(size_t)k * G3 + n] : 0.f;
    w1t[(size_t)n * EP + k] = (f16)v;
}

__global__ void k_w2f(const float* __restrict__ w2, f16* __restrict__ w2f) {
    int g    = blockIdx.x * 256 + threadIdx.x;
    int lane = g & 63;
    int kt   = (g >> 6) & 31;
    int nt   = g >> 11;
    int krow = kt * 32 + (lane >> 4) * 8;
    int n    = nt * 16 + (lane & 15);
    f16* dst = w2f + ((size_t)(nt * 32 + kt) * 64 + lane) * 8;
#pragma unroll
    for (int j = 0; j < 8; ++j)
        dst[j] = (f16)w2[(size_t)(krow + j) * G3 + n];
}

// h0 fp32 -> hx[0] fp16, published at agent scope
__global__ void k_hinit(const float* __restrict__ h0, f16* __restrict__ hx) {
    int i = blockIdx.x * 256 + threadIdx.x;        // dword pairs
    f16 a = (f16)h0[2 * i], b = (f16)h0[2 * i + 1];
    unsigned lo = *(unsigned short*)&a, hi = *(unsigned short*)&b;
    __hip_atomic_store((unsigned*)hx + i, lo | (hi << 16),
                       __ATOMIC_RELAXED, __HIP_MEMORY_SCOPE_AGENT);
}

// ---------------- input projection GEMM ----------------
__global__ __launch_bounds__(256) void k_xp(const f16* __restrict__ xe,
                                            const f16* __restrict__ w1t,
                                            const float* __restrict__ bias0,
                                            f16* __restrict__ xp) {
    __shared__ __align__(16) f16 As[128 * 32];
    __shared__ __align__(16) f16 Bs[128 * 32];
    const int tid  = threadIdx.x;
    const int lane = tid & 63;
    const int w    = tid >> 6;
    const int wm   = w >> 1, wn = w & 1;
    const int n0   = blockIdx.x * 128;
    const int m0   = blockIdx.y * 128;

    f32x4 acc[4][4];
    const f32x4 z4 = {0.f, 0.f, 0.f, 0.f};
#pragma unroll
    for (int i = 0; i < 4; ++i)
#pragma unroll
        for (int j = 0; j < 4; ++j) acc[i][j] = z4;

    for (int kk = 0; kk < EP / 32; ++kk) {
        int k0 = kk * 32;
        __syncthreads();
#pragma unroll
        for (int c = 0; c < 2; ++c) {
            int t2 = tid + 256 * c;
            int row = t2 >> 2, kq = t2 & 3;
            ((half8*)As)[t2] = *(const half8*)(xe  + (size_t)(m0 + row) * EP + k0 + kq * 8);
            ((half8*)Bs)[t2] = *(const half8*)(w1t + (size_t)(n0 + row) * EP + k0 + kq * 8);
        }
        __syncthreads();
        half8 a[4], b[4];
#pragma unroll
        for (int i = 0; i < 4; ++i) {
            a[i] = ((half8*)As)[(wm * 64 + i * 16 + (lane & 15)) * 4 + (lane >> 4)];
            b[i] = ((half8*)Bs)[(wn * 64 + i * 16 + (lane & 15)) * 4 + (lane >> 4)];
        }
#pragma unroll
        for (int i = 0; i < 4; ++i)
#pragma unroll
            for (int j = 0; j < 4; ++j)
                acc[i][j] = __builtin_amdgcn_mfma_f32_16x16x32_f16(a[i], b[j], acc[i][j], 0, 0, 0);
    }

    float bv[4];
#pragma unroll
    for (int j = 0; j < 4; ++j) bv[j] = bias0[n0 + wn * 64 + j * 16 + (lane & 15)];
#pragma unroll
    for (int i = 0; i < 4; ++i)
#pragma unroll
        for (int j = 0; j < 4; ++j)
#pragma unroll
            for (int e = 0; e < 4; ++e) {
                int rl  = wm * 64 + i * 16 + (lane >> 4) * 4 + e;
                int bt  = m0 + rl;
                int tt  = bt & (T_ - 1);
                int bb  = bt >> 9;
                int col = n0 + wn * 64 + j * 16 + (lane & 15);
                xp[((size_t)tt * B_ + bb) * G3 + col] = (f16)(acc[i][j][e] + bv[j]);
            }
}

// ---------------- persistent GRU recurrence ----------------
// 128 blocks x 512 threads. rw = blk&3 (16 batch rows), ut2 = blk>>2 (32 u).
// Waves: uw = wave>>2 (u-tile), kw = wave&3 (K chunk of 256).
// A-fragments (h state) are loaded DIRECTLY from global hx in MFMA fragment
// layout (16B/lane, 64B segments per batch row) -> no LDS staging round-trip,
// no pre-MFMA block barrier. Only the K-reduce buffer lives in LDS.
// red lane-dim padded 64->65: makes the w2-slab stride = 4 mod 32 so the two
// uwq halves read disjoint bank sets (was a 4-way conflict on every b32 read).
__global__ __launch_bounds__(512, 2) void k_rec(const f16* __restrict__ xp,
                                                const f16* __restrict__ w2f,
                                                const float* __restrict__ bias1,
                                                const float* __restrict__ h0,
                                                f16* __restrict__ hx,
                                                float* __restrict__ out,
                                                unsigned* __restrict__ ctr) {
    const int tid  = threadIdx.x;
    const int lane = tid & 63;
    const int wave = tid >> 6;          // 0..7
    const int uw   = wave >> 2;         // 0..1
    const int kw   = wave & 3;          // 0..3
    const int rw   = blockIdx.x & 3;
    const int ut2  = blockIdx.x >> 2;   // 0..31
    const int ut16 = ut2 * 2 + uw;      // 16-u tile id 0..63

    __shared__ __align__(16) float red[8][3][65][4];    // ~24.4 KB K-partials

    // resident weights: opaque asm loads -> pinned in VGPRs (96 regs)
    half8 bw[3][8];
#pragma unroll
    for (int g = 0; g < 3; ++g) {
        int nt = g * 64 + ut16;
#pragma unroll
        for (int k8 = 0; k8 < 8; ++k8) {
            int kt = kw * 8 + k8;
            const f16* src = w2f + ((size_t)(nt * 32 + kt) * 64 + lane) * 8;
            WLOAD(bw[g][k8], src);
        }
    }
    VMFENCE();

    const int row  = tid >> 5;          // 0..15
    const int u32  = tid & 31;          // 0..31
    const int rowg = rw * 16 + row;     // global batch row
    const int ug   = ut2 * 32 + u32;    // hidden unit
    float h = h0[rowg * U_ + ug];       // fp32 state in register
    const float bz = bias1[ug], br = bias1[U_ + ug], bh = bias1[2 * U_ + ug];
    const int lsrc = (row >> 2) * 16 + (u32 & 15);
    const int ei   = row & 3;
    const int uwq  = u32 >> 4;
    const f32x4 z4 = {0.f, 0.f, 0.f, 0.f};
    unsigned* myctr = ctr + rw * 2048;  // per-group private counter page

    // per-lane A-fragment base: row = lane&15 of this rw group, K chunk of kw,
    // 16B sub-chunk = lane>>4. af[k8] is +k8*64 bytes from here.
    const f16* afb = hx + (size_t)(rw * 16 + (lane & 15)) * U_
                        + (size_t)kw * 256 + (size_t)(lane >> 4) * 8;
    float* outrow = out + (size_t)rowg * T_ * U_ + ug;

    // xp prefetch for t=0
    const f16* xpb = xp + (size_t)rowg * G3 + ug;
    float xz = (float)xpb[0], xr = (float)xpb[(size_t)U_], xh = (float)xpb[(size_t)2 * U_];

#pragma unroll 1
    for (int t = 0; t < T_; ++t) {
        // ---- 1. A fragments direct from global (L1/L2-bypass, fragment layout) ----
        const f16* ga = afb + (size_t)(t & 1) * (B_ * U_);
        half8 af[8];
        CLOADO(af[0], ga, "0");
        CLOADO(af[1], ga, "64");
        CLOADO(af[2], ga, "128");
        CLOADO(af[3], ga, "192");
        CLOADO(af[4], ga, "256");
        CLOADO(af[5], ga, "320");
        CLOADO(af[6], ga, "384");
        CLOADO(af[7], ga, "448");
        VMFENCE();   // af feeds MFMA (register-only) -> waitcnt + sched fence

        // ---- 2. MFMA ----
        f32x4 acc[3] = {z4, z4, z4};
#pragma unroll
        for (int k8 = 0; k8 < 8; ++k8)
#pragma unroll
            for (int g = 0; g < 3; ++g)
                acc[g] = __builtin_amdgcn_mfma_f32_16x16x32_f16(af[k8], bw[g][k8], acc[g], 0, 0, 0);

        // ---- 3. out store for h_{t-1}: issued after the MFMA-critical drain;
        //         its ack is covered by the end-of-step __syncthreads ----
        if (t) outrow[(size_t)(t - 1) * U_] = h;

        // ---- 4. K-reduce partials -> LDS ----
#pragma unroll
        for (int g = 0; g < 3; ++g)
            *(f32x4*)&red[wave][g][lane][0] = acc[g];

        // ---- 5. prefetch xp for t+1 (latency hides under barrier + reduce) ----
        int tn = (t < T_ - 1) ? t + 1 : t;
        const f16* xpn = xp + ((size_t)tn * B_ + rowg) * G3 + ug;
        float xzn = (float)xpn[0], xrn = (float)xpn[(size_t)U_], xhn = (float)xpn[(size_t)2 * U_];

        barrier_lds();

        float sz = 0.f, sr = 0.f, sh = 0.f;
#pragma unroll
        for (int k2 = 0; k2 < 4; ++k2) {
            int w2 = uwq * 4 + k2;
            sz += red[w2][0][lsrc][ei];
            sr += red[w2][1][lsrc][ei];
            sh += red[w2][2][lsrc][ei];
        }

        // ---- 6. epilogue ----
        float zg = 1.f / (1.f + expf(-(xz + sz + bz)));
        float rg = 1.f / (1.f + expf(-(xr + sr + br)));
        float hh = tanhf(xh + rg * (sh + bh));
        h = zg * h + (1.f - zg) * hh;

        // publish h_t (fp16 pair, write-through to coherent point)
        f16 hf = (f16)h;
        unsigned my = *(unsigned short*)&hf;
        unsigned nb = __shfl_down(my, 1);
        if ((u32 & 1) == 0) {
            unsigned* dst = (unsigned*)(hx + (size_t)((t + 1) & 1) * (B_ * U_)
                                        + (size_t)rowg * U_ + ug);
            __hip_atomic_store(dst, my | (nb << 16),
                               __ATOMIC_RELAXED, __HIP_MEMORY_SCOPE_AGENT);
        }

        // ---- 7. group barrier (drains hx + out stores via __syncthreads) ----
        __syncthreads();
        if (tid == 0) {
            __hip_atomic_fetch_add(myctr + t, 1u,
                                   __ATOMIC_RELAXED, __HIP_MEMORY_SCOPE_AGENT);
            while (__hip_atomic_load(myctr + t,
                                     __ATOMIC_RELAXED, __HIP_MEMORY_SCOPE_AGENT) < 32u)
                __builtin_amdgcn_s_sleep(1);
        }
        __syncthreads();

        xz = xzn; xr = xrn; xh = xhn;
    }
    outrow[(size_t)(T_ - 1) * U_] = h;
    out[(size_t)B_ * T_ * U_ + (size_t)rowg * U_ + ug] = h;
}

// ---------------- host ----------------
extern "C" void kernel_launch(void* const* d_in, const int* in_sizes, int n_in,
                              void* d_out, int out_size, void* d_ws, size_t ws_size,
                              hipStream_t stream) {
    const int*   x    = (const int*)d_in[0];
    const float* h0   = (const float*)d_in[1];
    const float* emb  = (const float*)d_in[2];
    const float* w1   = (const float*)d_in[3];
    const float* w2   = (const float*)d_in[4];
    const float* bias = (const float*)d_in[5];
    float* out = (float*)d_out;
    char*  ws  = (char*)d_ws;

    f16*      xe   = (f16*)(ws + OFF_XE);
    f16*      w1t  = (f16*)(ws + OFF_W1T);
    f16*      w2f  = (f16*)(ws + OFF_W2F);
    f16*      xp   = (f16*)(ws + OFF_XP);
    f16*      hx   = (f16*)(ws + OFF_HX);     // time-shared with xe
    unsigned* ctr  = (unsigned*)(ws + OFF_CTR2);

    k_gather<<<B_ * T_ / 4, 256, 0, stream>>>(x, emb, xe);
    k_w1t<<<G3, EP, 0, stream>>>(w1, w1t);
    k_w2f<<<(192 * 32 * 64) / 256, 256, 0, stream>>>(w2, w2f);
    k_xp<<<dim3(G3 / 128, B_ * T_ / 128), 256, 0, stream>>>(xe, w1t, bias, xp);

    // xe region is dead now; hx/ctr live inside it
    hipMemsetAsync(ctr, 0, 4 * 2048 * sizeof(unsigned), stream);
    k_hinit<<<(B_ * U_ / 2) / 256, 256, 0, stream>>>(h0, hx);

    const f16*   xp_c   = xp;
    const f16*   w2f_c  = w2f;
    const float* bias1  = bias + G3;
    void* args[] = {(void*)&xp_c, (void*)&w2f_c, (void*)&bias1, (void*)&h0,
                    (void*)&hx, (void*)&out, (void*)&ctr};
    if (hipLaunchCooperativeKernel((const void*)k_rec, dim3(128), dim3(512),
                                   args, 0, stream) != hipSuccess) {
        k_rec<<<128, 512, 0, stream>>>(xp_c, w2f_c, bias1, h0, hx, out, ctr);
    }
}

// Round 4
// 1594.942 us; speedup vs baseline: 1.3854x; 1.3854x over previous
//
#include <hip/hip_runtime.h>

typedef _Float16 f16;
typedef _Float16 half8 __attribute__((ext_vector_type(8)));
typedef float f32x4 __attribute__((ext_vector_type(4)));
typedef unsigned long long u64;

#define B_  64
#define T_  512
#define V_  32000
#define E_  300
#define EP  320      // E padded to multiple of 32 for MFMA K
#define U_  1024
#define G3  3072     // 3*U

// ---- workspace layout (bytes) ----
// XE region is time-shared: k_gather/k_xp use it first, then hx/flags live in it.
#define OFF_XE   0ull
#define OFF_HX   OFF_XE                               // hx[2][64][1024] fp16 (256 KB)
#define OFF_CTR2 (OFF_XE + 2ull*B_*U_*2)              // flags[4][2048] dwords (32 KB)
#define OFF_W1T  (OFF_XE  + (size_t)B_*T_*EP*2)       // xe fp16 [32768][320]
#define OFF_W2F  (OFF_W1T + (size_t)G3*EP*2)
#define OFF_XP   (OFF_W2F + (size_t)U_*G3*2)

__device__ __forceinline__ void barrier_lds() {
    // LDS-only dependency barrier: don't drain vmcnt (keeps prefetches alive)
    asm volatile("s_waitcnt lgkmcnt(0)\n\ts_barrier" ::: "memory");
}

// opaque 16B load: result is an asm output -> cannot be rematerialized, so
// the allocator must keep it in VGPRs for its whole live range
#define WLOAD(dst, src) \
    asm volatile("global_load_dwordx4 %0, %1, off" : "=v"(dst) : "v"(src) : "memory")
// L1/L2-bypassing 16B load (coherent at L3; producers drained theirs pre-barrier)
#define CLOAD(dst, src) \
    asm volatile("global_load_dwordx4 %0, %1, off sc0 sc1" : "=v"(dst) : "v"(src) : "memory")
// vmcnt drain whose protected values feed register-only consumers would need
// sched_barrier(0) too (rule #18); here drains feed LDS writes (memory ops),
// which the "memory" clobber orders.
#define VMFENCE() do {                                      \
    asm volatile("s_waitcnt vmcnt(0)" ::: "memory");        \
    __builtin_amdgcn_sched_barrier(0);                      \
} while (0)

// ---------------- setup kernels ----------------

__global__ void k_gather(const int* __restrict__ x, const float* __restrict__ emb,
                         f16* __restrict__ xe) {
    int row  = blockIdx.x * 4 + (threadIdx.x >> 6);
    int lane = threadIdx.x & 63;
    int tok  = x[row];
    const float* er = emb + (size_t)tok * E_;
    f16* xr = xe + (size_t)row * EP;
#pragma unroll
    for (int e = lane; e < EP; e += 64) {
        float v = (e < E_) ? er[e] : 0.f;
        xr[e] = (f16)v;
    }
}

__global__ void k_w1t(const float* __restrict__ w1, f16* __restrict__ w1t) {
    int n = blockIdx.x;
    int k = threadIdx.x;
    float v = (k < E_) ? w1[(size_t)k * G3 + n] : 0.f;
    w1t[(size_t)n * EP + k] = (f16)v;
}

__global__ void k_w2f(const float* __restrict__ w2, f16* __restrict__ w2f) {
    int g    = blockIdx.x * 256 + threadIdx.x;
    int lane = g & 63;
    int kt   = (g >> 6) & 31;
    int nt   = g >> 11;
    int krow = kt * 32 + (lane >> 4) * 8;
    int n    = nt * 16 + (lane & 15);
    f16* dst = w2f + ((size_t)(nt * 32 + kt) * 64 + lane) * 8;
#pragma unroll
    for (int j = 0; j < 8; ++j)
        dst[j] = (f16)w2[(size_t)(krow + j) * G3 + n];
}

// h0 fp32 -> hx[0] fp16, published at agent scope
__global__ void k_hinit(const float* __restrict__ h0, f16* __restrict__ hx) {
    int i = blockIdx.x * 256 + threadIdx.x;        // dword pairs
    f16 a = (f16)h0[2 * i], b = (f16)h0[2 * i + 1];
    unsigned lo = *(unsigned short*)&a, hi = *(unsigned short*)&b;
    __hip_atomic_store((unsigned*)hx + i, lo | (hi << 16),
                       __ATOMIC_RELAXED, __HIP_MEMORY_SCOPE_AGENT);
}

// ---------------- input projection GEMM ----------------
__global__ __launch_bounds__(256) void k_xp(const f16* __restrict__ xe,
                                            const f16* __restrict__ w1t,
                                            const float* __restrict__ bias0,
                                            f16* __restrict__ xp) {
    __shared__ __align__(16) f16 As[128 * 32];
    __shared__ __align__(16) f16 Bs[128 * 32];
    const int tid  = threadIdx.x;
    const int lane = tid & 63;
    const int w    = tid >> 6;
    const int wm   = w >> 1, wn = w & 1;
    const int n0   = blockIdx.x * 128;
    const int m0   = blockIdx.y * 128;

    f32x4 acc[4][4];
    const f32x4 z4 = {0.f, 0.f, 0.f, 0.f};
#pragma unroll
    for (int i = 0; i < 4; ++i)
#pragma unroll
        for (int j = 0; j < 4; ++j) acc[i][j] = z4;

    for (int kk = 0; kk < EP / 32; ++kk) {
        int k0 = kk * 32;
        __syncthreads();
#pragma unroll
        for (int c = 0; c < 2; ++c) {
            int t2 = tid + 256 * c;
            int row = t2 >> 2, kq = t2 & 3;
            ((half8*)As)[t2] = *(const half8*)(xe  + (size_t)(m0 + row) * EP + k0 + kq * 8);
            ((half8*)Bs)[t2] = *(const half8*)(w1t + (size_t)(n0 + row) * EP + k0 + kq * 8);
        }
        __syncthreads();
        half8 a[4], b[4];
#pragma unroll
        for (int i = 0; i < 4; ++i) {
            a[i] = ((half8*)As)[(wm * 64 + i * 16 + (lane & 15)) * 4 + (lane >> 4)];
            b[i] = ((half8*)Bs)[(wn * 64 + i * 16 + (lane & 15)) * 4 + (lane >> 4)];
        }
#pragma unroll
        for (int i = 0; i < 4; ++i)
#pragma unroll
            for (int j = 0; j < 4; ++j)
                acc[i][j] = __builtin_amdgcn_mfma_f32_16x16x32_f16(a[i], b[j], acc[i][j], 0, 0, 0);
    }

    float bv[4];
#pragma unroll
    for (int j = 0; j < 4; ++j) bv[j] = bias0[n0 + wn * 64 + j * 16 + (lane & 15)];
#pragma unroll
    for (int i = 0; i < 4; ++i)
#pragma unroll
        for (int j = 0; j < 4; ++j)
#pragma unroll
            for (int e = 0; e < 4; ++e) {
                int rl  = wm * 64 + i * 16 + (lane >> 4) * 4 + e;
                int bt  = m0 + rl;
                int tt  = bt & (T_ - 1);
                int bb  = bt >> 9;
                int col = n0 + wn * 64 + j * 16 + (lane & 15);
                xp[((size_t)tt * B_ + bb) * G3 + col] = (f16)(acc[i][j][e] + bv[j]);
            }
}

// ---------------- persistent GRU recurrence ----------------
// 128 blocks x 512 threads. rw = blk&3 (16 batch rows), ut2 = blk>>2 (32 u).
// Waves: uw = wave>>2 (u-tile), kw = wave&3 (K chunk of 256).
// hs is XOR-swizzled at 16B granularity: physical unit = logical ^ (row&7)
// (fixes the 16-way bank conflict on af ds_read_b128; measured -1e8 cyc).
// red is [..][64][5]: ei-stride 1, lane-stride 5 dwords -> scalar reduce reads
// spread over 16+ banks (5 coprime 32) instead of the 4-dword lattice that made
// them 4-way conflicted ([65][4] left 3.8e7 conflict cycles; uwq offset 16 is
// still on the 4-lattice). Writes become 4x b32 at stride 5: 2-way, free.
// Group sync: per-producer flag slots (128B apart) + 64-lane ballot poll
// replaces 32 same-line atomic RMWs (which serialize at the LLC bank).
__global__ __launch_bounds__(512, 2) void k_rec(const f16* __restrict__ xp,
                                                const f16* __restrict__ w2f,
                                                const float* __restrict__ bias1,
                                                const float* __restrict__ h0,
                                                f16* __restrict__ hx,
                                                float* __restrict__ out,
                                                unsigned* __restrict__ ctr) {
    const int tid  = threadIdx.x;
    const int lane = tid & 63;
    const int wave = tid >> 6;          // 0..7
    const int uw   = wave >> 2;         // 0..1
    const int kw   = wave & 3;          // 0..3
    const int rw   = blockIdx.x & 3;
    const int ut2  = blockIdx.x >> 2;   // 0..31
    const int ut16 = ut2 * 2 + uw;      // 16-u tile id 0..63

    __shared__ __align__(16) f16   hs[16 * 1024];       // 32 KB staged h (swizzled)
    __shared__ __align__(16) float red[8][3][64][5];    // 30 KB K-partials (stride-5)

    // resident weights: opaque asm loads -> pinned in VGPRs (96 regs)
    half8 bw[3][8];
#pragma unroll
    for (int g = 0; g < 3; ++g) {
        int nt = g * 64 + ut16;
#pragma unroll
        for (int k8 = 0; k8 < 8; ++k8) {
            int kt = kw * 8 + k8;
            const f16* src = w2f + ((size_t)(nt * 32 + kt) * 64 + lane) * 8;
            WLOAD(bw[g][k8], src);
        }
    }
    VMFENCE();

    const int row  = tid >> 5;          // 0..15
    const int u32  = tid & 31;          // 0..31
    const int rowg = rw * 16 + row;     // global batch row
    const int ug   = ut2 * 32 + u32;    // hidden unit
    float h = h0[rowg * U_ + ug];       // fp32 state in register
    const float bz = bias1[ug], br = bias1[U_ + ug], bh = bias1[2 * U_ + ug];
    const int lsrc = (row >> 2) * 16 + (u32 & 15);
    const int ei   = row & 3;
    const int uwq  = u32 >> 4;
    const f32x4 z4 = {0.f, 0.f, 0.f, 0.f};
    unsigned* myflags = ctr + rw * 2048;   // per-group flag page, slot = ut2*32

    // stage geometry: thread moves 4x16B blocks; swizzled dest unit = u32 ^ (row&7)
    const f16* gsb = hx + (size_t)rowg * U_ + (size_t)u32 * 8; // +32*8*i halves
    half8* ldsdst  = (half8*)(hs + row * 1024) + (u32 ^ (row & 7));
    // read side: same permutation, per-16B-unit within the row
    const int rrow = lane & 15;
    const int rsw  = rrow & 7;
    const f16* hrow = hs + rrow * 1024 + kw * 256;
    const int rq   = lane >> 4;
    float* outrow = out + (size_t)rowg * T_ * U_ + ug;

    // xp prefetch for t=0
    const f16* xpb = xp + (size_t)rowg * G3 + ug;
    float xz = (float)xpb[0], xr = (float)xpb[(size_t)U_], xh = (float)xpb[(size_t)2 * U_];

#pragma unroll 1
    for (int t = 0; t < T_; ++t) {
        // ---- 1. stage hx[t&1] -> LDS (L1/L2-bypass loads, issued at release) ----
        const f16* gs = gsb + (size_t)(t & 1) * (B_ * U_);
        half8 v0, v1, v2, v3;
        CLOAD(v0, gs);
        CLOAD(v1, gs + 256);
        CLOAD(v2, gs + 512);
        CLOAD(v3, gs + 768);
        asm volatile("s_waitcnt vmcnt(0)" ::: "memory");
        ldsdst[0]  = v0;
        ldsdst[32] = v1;
        ldsdst[64] = v2;
        ldsdst[96] = v3;
        // out store for h_{t-1}: off the critical path (drains ~2000cy later)
        if (t) outrow[(size_t)(t - 1) * U_] = h;
        barrier_lds();

        // ---- 2. A fragments from LDS (16-lane broadcast reads, swizzled) ----
        half8 af[8];
#pragma unroll
        for (int k8 = 0; k8 < 8; ++k8)
            af[k8] = *(const half8*)(hrow + (((rq + 4 * k8) ^ rsw) << 3));

        // ---- 3. prefetch xp for t+1 ----
        int tn = (t < T_ - 1) ? t + 1 : t;
        const f16* xpn = xp + ((size_t)tn * B_ + rowg) * G3 + ug;
        float xzn = (float)xpn[0], xrn = (float)xpn[(size_t)U_], xhn = (float)xpn[(size_t)2 * U_];

        // ---- 4. MFMA ----
        f32x4 acc[3] = {z4, z4, z4};
#pragma unroll
        for (int k8 = 0; k8 < 8; ++k8)
#pragma unroll
            for (int g = 0; g < 3; ++g)
                acc[g] = __builtin_amdgcn_mfma_f32_16x16x32_f16(af[k8], bw[g][k8], acc[g], 0, 0, 0);

        // ---- 5. K-reduce via LDS (scalar b32 writes, stride 5 -> 2-way free) ----
#pragma unroll
        for (int g = 0; g < 3; ++g)
#pragma unroll
            for (int e = 0; e < 4; ++e)
                red[wave][g][lane][e] = acc[g][e];
        barrier_lds();

        float sz = 0.f, sr = 0.f, sh = 0.f;
#pragma unroll
        for (int k2 = 0; k2 < 4; ++k2) {
            int w2 = uwq * 4 + k2;
            sz += red[w2][0][lsrc][ei];
            sr += red[w2][1][lsrc][ei];
            sh += red[w2][2][lsrc][ei];
        }

        // ---- 6. epilogue ----
        float zg = 1.f / (1.f + expf(-(xz + sz + bz)));
        float rg = 1.f / (1.f + expf(-(xr + sr + br)));
        float hh = tanhf(xh + rg * (sh + bh));
        h = zg * h + (1.f - zg) * hh;

        // publish h_t (fp16 pair, write-through to coherent point)
        f16 hf = (f16)h;
        unsigned my = *(unsigned short*)&hf;
        unsigned nb = __shfl_down(my, 1);
        if ((u32 & 1) == 0) {
            unsigned* dst = (unsigned*)(hx + (size_t)((t + 1) & 1) * (B_ * U_)
                                        + (size_t)rowg * U_ + ug);
            __hip_atomic_store(dst, my | (nb << 16),
                               __ATOMIC_RELAXED, __HIP_MEMORY_SCOPE_AGENT);
        }

        // ---- 7. group barrier: __syncthreads drains all hx/out stores, then
        //         one flag store per block + 64-lane ballot poll ----
        __syncthreads();
        if (wave == 0) {
            if (lane == 0)
                __hip_atomic_store(myflags + ut2 * 32, (unsigned)(t + 1),
                                   __ATOMIC_RELAXED, __HIP_MEMORY_SCOPE_AGENT);
            const unsigned* pf = myflags + (lane & 31) * 32;
            unsigned v;
            do {
                v = __hip_atomic_load(pf, __ATOMIC_RELAXED, __HIP_MEMORY_SCOPE_AGENT);
            } while (__ballot(v < (unsigned)(t + 1)) != 0ull);
        }
        __syncthreads();

        xz = xzn; xr = xrn; xh = xhn;
    }
    outrow[(size_t)(T_ - 1) * U_] = h;
    out[(size_t)B_ * T_ * U_ + (size_t)rowg * U_ + ug] = h;
}

// ---------------- host ----------------
extern "C" void kernel_launch(void* const* d_in, const int* in_sizes, int n_in,
                              void* d_out, int out_size, void* d_ws, size_t ws_size,
                              hipStream_t stream) {
    const int*   x    = (const int*)d_in[0];
    const float* h0   = (const float*)d_in[1];
    const float* emb  = (const float*)d_in[2];
    const float* w1   = (const float*)d_in[3];
    const float* w2   = (const float*)d_in[4];
    const float* bias = (const float*)d_in[5];
    float* out = (float*)d_out;
    char*  ws  = (char*)d_ws;

    f16*      xe   = (f16*)(ws + OFF_XE);
    f16*      w1t  = (f16*)(ws + OFF_W1T);
    f16*      w2f  = (f16*)(ws + OFF_W2F);
    f16*      xp   = (f16*)(ws + OFF_XP);
    f16*      hx   = (f16*)(ws + OFF_HX);     // time-shared with xe
    unsigned* ctr  = (unsigned*)(ws + OFF_CTR2);

    k_gather<<<B_ * T_ / 4, 256, 0, stream>>>(x, emb, xe);
    k_w1t<<<G3, EP, 0, stream>>>(w1, w1t);
    k_w2f<<<(192 * 32 * 64) / 256, 256, 0, stream>>>(w2, w2f);
    k_xp<<<dim3(G3 / 128, B_ * T_ / 128), 256, 0, stream>>>(xe, w1t, bias, xp);

    // xe region is dead now; hx/flags live inside it
    hipMemsetAsync(ctr, 0, 4 * 2048 * sizeof(unsigned), stream);
    k_hinit<<<(B_ * U_ / 2) / 256, 256, 0, stream>>>(h0, hx);

    const f16*   xp_c   = xp;
    const f16*   w2f_c  = w2f;
    const float* bias1  = bias + G3;
    void* args[] = {(void*)&xp_c, (void*)&w2f_c, (void*)&bias1, (void*)&h0,
                    (void*)&hx, (void*)&out, (void*)&ctr};
    if (hipLaunchCooperativeKernel((const void*)k_rec, dim3(128), dim3(512),
                                   args, 0, stream) != hipSuccess) {
        k_rec<<<128, 512, 0, stream>>>(xp_c, w2f_c, bias1, h0, hx, out, ctr);
    }
}

// Round 5
// 1388.950 us; speedup vs baseline: 1.5908x; 1.1483x over previous
//
#include <hip/hip_runtime.h>

typedef _Float16 f16;
typedef _Float16 half8 __attribute__((ext_vector_type(8)));
typedef float f32x4 __attribute__((ext_vector_type(4)));
typedef unsigned u32x4 __attribute__((ext_vector_type(4)));
typedef unsigned long long u64;

#define B_  64
#define T_  512
#define V_  32000
#define E_  300
#define EP  320      // E padded to multiple of 32 for MFMA K
#define U_  1024
#define G3  3072     // 3*U
#define BU  (B_ * U_)            // one h buffer, elements
#define BUB (B_ * U_ * 2)        // one h buffer, bytes (128 KB)

// ---- workspace layout (bytes) ----
// XE region is time-shared: k_gather/k_xp use it first, then hx lives in it.
// hx[3][64][1024] fp16 = 384 KB, parity-tagged triple buffer.
#define OFF_XE   0ull
#define OFF_HX   OFF_XE
#define OFF_W1T  (OFF_XE  + (size_t)B_*T_*EP*2)       // xe fp16 [32768][320]
#define OFF_W2F  (OFF_W1T + (size_t)G3*EP*2)
#define OFF_XP   (OFF_W2F + (size_t)U_*G3*2)

__device__ __forceinline__ void barrier_lds() {
    // LDS-only dependency barrier: don't drain vmcnt (keeps prefetches alive)
    asm volatile("s_waitcnt lgkmcnt(0)\n\ts_barrier" ::: "memory");
}

// opaque 16B load: result is an asm output -> cannot be rematerialized, so
// the allocator must keep it in VGPRs for its whole live range
#define WLOAD(dst, src) \
    asm volatile("global_load_dwordx4 %0, %1, off" : "=v"(dst) : "v"(src) : "memory")
// L1/L2-bypassing 16B load (coherent at L3)
#define CLOAD(dst, src) \
    asm volatile("global_load_dwordx4 %0, %1, off sc0 sc1" : "=v"(dst) : "v"(src) : "memory")
// vmcnt drain whose protected values feed REGISTER-ONLY consumers (VALU parity
// checks / MFMA): needs sched_barrier(0) or hipcc hoists the consumer past the
// waitcnt (rule #18 — "memory" clobber doesn't order non-memory instructions).
#define VMFENCE() do {                                      \
    asm volatile("s_waitcnt vmcnt(0)" ::: "memory");        \
    __builtin_amdgcn_sched_barrier(0);                      \
} while (0)

// ---------------- setup kernels ----------------

__global__ void k_gather(const int* __restrict__ x, const float* __restrict__ emb,
                         f16* __restrict__ xe) {
    int row  = blockIdx.x * 4 + (threadIdx.x >> 6);
    int lane = threadIdx.x & 63;
    int tok  = x[row];
    const float* er = emb + (size_t)tok * E_;
    f16* xr = xe + (size_t)row * EP;
#pragma unroll
    for (int e = lane; e < EP; e += 64) {
        float v = (e < E_) ? er[e] : 0.f;
        xr[e] = (f16)v;
    }
}

__global__ void k_w1t(const float* __restrict__ w1, f16* __restrict__ w1t) {
    int n = blockIdx.x;
    int k = threadIdx.x;
    float v = (k < E_) ? w1[(size_t)k * G3 + n] : 0.f;
    w1t[(size_t)n * EP + k] = (f16)v;
}

__global__ void k_w2f(const float* __restrict__ w2, f16* __restrict__ w2f) {
    int g    = blockIdx.x * 256 + threadIdx.x;
    int lane = g & 63;
    int kt   = (g >> 6) & 31;
    int nt   = g >> 11;
    int krow = kt * 32 + (lane >> 4) * 8;
    int n    = nt * 16 + (lane & 15);
    f16* dst = w2f + ((size_t)(nt * 32 + kt) * 64 + lane) * 8;
#pragma unroll
    for (int j = 0; j < 8; ++j)
        dst[j] = (f16)w2[(size_t)(krow + j) * G3 + n];
}

// h0 fp32 -> hx[0] fp16 with LSB forced to parity 1 (generation tag for t=0),
// published at agent scope. h0 is all-zeros; LSB=1 makes it the smallest
// subnormal (~6e-8) — negligible.
__global__ void k_hinit(const float* __restrict__ h0, f16* __restrict__ hx) {
    int i = blockIdx.x * 256 + threadIdx.x;        // dword pairs
    f16 a = (f16)h0[2 * i], b = (f16)h0[2 * i + 1];
    unsigned lo = (*(unsigned short*)&a) | 1u, hi = (*(unsigned short*)&b) | 1u;
    __hip_atomic_store((unsigned*)hx + i, lo | (hi << 16),
                       __ATOMIC_RELAXED, __HIP_MEMORY_SCOPE_AGENT);
}

// ---------------- input projection GEMM ----------------
__global__ __launch_bounds__(256) void k_xp(const f16* __restrict__ xe,
                                            const f16* __restrict__ w1t,
                                            const float* __restrict__ bias0,
                                            f16* __restrict__ xp) {
    __shared__ __align__(16) f16 As[128 * 32];
    __shared__ __align__(16) f16 Bs[128 * 32];
    const int tid  = threadIdx.x;
    const int lane = tid & 63;
    const int w    = tid >> 6;
    const int wm   = w >> 1, wn = w & 1;
    const int n0   = blockIdx.x * 128;
    const int m0   = blockIdx.y * 128;

    f32x4 acc[4][4];
    const f32x4 z4 = {0.f, 0.f, 0.f, 0.f};
#pragma unroll
    for (int i = 0; i < 4; ++i)
#pragma unroll
        for (int j = 0; j < 4; ++j) acc[i][j] = z4;

    for (int kk = 0; kk < EP / 32; ++kk) {
        int k0 = kk * 32;
        __syncthreads();
#pragma unroll
        for (int c = 0; c < 2; ++c) {
            int t2 = tid + 256 * c;
            int row = t2 >> 2, kq = t2 & 3;
            ((half8*)As)[t2] = *(const half8*)(xe  + (size_t)(m0 + row) * EP + k0 + kq * 8);
            ((half8*)Bs)[t2] = *(const half8*)(w1t + (size_t)(n0 + row) * EP + k0 + kq * 8);
        }
        __syncthreads();
        half8 a[4], b[4];
#pragma unroll
        for (int i = 0; i < 4; ++i) {
            a[i] = ((half8*)As)[(wm * 64 + i * 16 + (lane & 15)) * 4 + (lane >> 4)];
            b[i] = ((half8*)Bs)[(wn * 64 + i * 16 + (lane & 15)) * 4 + (lane >> 4)];
        }
#pragma unroll
        for (int i = 0; i < 4; ++i)
#pragma unroll
            for (int j = 0; j < 4; ++j)
                acc[i][j] = __builtin_amdgcn_mfma_f32_16x16x32_f16(a[i], b[j], acc[i][j], 0, 0, 0);
    }

    float bv[4];
#pragma unroll
    for (int j = 0; j < 4; ++j) bv[j] = bias0[n0 + wn * 64 + j * 16 + (lane & 15)];
#pragma unroll
    for (int i = 0; i < 4; ++i)
#pragma unroll
        for (int j = 0; j < 4; ++j)
#pragma unroll
            for (int e = 0; e < 4; ++e) {
                int rl  = wm * 64 + i * 16 + (lane >> 4) * 4 + e;
                int bt  = m0 + rl;
                int tt  = bt & (T_ - 1);
                int bb  = bt >> 9;
                int col = n0 + wn * 64 + j * 16 + (lane & 15);
                xp[((size_t)tt * B_ + bb) * G3 + col] = (f16)(acc[i][j][e] + bv[j]);
            }
}

// ---------------- persistent GRU recurrence ----------------
// 128 blocks x 512 threads. rw = blk&3 (16 batch rows), ut2 = blk>>2 (32 u).
// SYNC-FREE h exchange: publish h_t into hx[(t+1)%3] with every fp16's LSB
// forced to parity (t&1). Consumers poll the data itself (per-dword parity
// check) — no flags, no group barrier, no publish-ack drain. Dataflow bounds
// block spread to <=1 step; with 3 buffers and odd rotation distance the
// parity uniquely identifies the wanted generation (stale/future differ).
// hs is XOR-swizzled at 16B granularity: physical unit = logical ^ (row&7).
// red is [..][64][5]: lane-stride 5 dwords -> reduce reads ~conflict-free.
__global__ __launch_bounds__(512, 2) void k_rec(const f16* __restrict__ xp,
                                                const f16* __restrict__ w2f,
                                                const float* __restrict__ bias1,
                                                const float* __restrict__ h0,
                                                f16* __restrict__ hx,
                                                float* __restrict__ out) {
    const int tid  = threadIdx.x;
    const int lane = tid & 63;
    const int wave = tid >> 6;          // 0..7
    const int uw   = wave >> 2;         // 0..1
    const int kw   = wave & 3;          // 0..3
    const int rw   = blockIdx.x & 3;
    const int ut2  = blockIdx.x >> 2;   // 0..31
    const int ut16 = ut2 * 2 + uw;      // 16-u tile id 0..63

    __shared__ __align__(16) f16   hs[16 * 1024];       // 32 KB staged h (swizzled)
    __shared__ __align__(16) float red[8][3][64][5];    // 30 KB K-partials (stride-5)

    // resident weights: opaque asm loads -> pinned in VGPRs
    half8 bw[3][8];
#pragma unroll
    for (int g = 0; g < 3; ++g) {
        int nt = g * 64 + ut16;
#pragma unroll
        for (int k8 = 0; k8 < 8; ++k8) {
            int kt = kw * 8 + k8;
            const f16* src = w2f + ((size_t)(nt * 32 + kt) * 64 + lane) * 8;
            WLOAD(bw[g][k8], src);
        }
    }
    VMFENCE();

    const int row  = tid >> 5;          // 0..15
    const int u32  = tid & 31;          // 0..31
    const int rowg = rw * 16 + row;     // global batch row
    const int ug   = ut2 * 32 + u32;    // hidden unit
    float h = h0[rowg * U_ + ug];       // fp32 state in register
    const float bz = bias1[ug], br = bias1[U_ + ug], bh = bias1[2 * U_ + ug];
    const int lsrc = (row >> 2) * 16 + (u32 & 15);
    const int ei   = row & 3;
    const int uwq  = u32 >> 4;
    const f32x4 z4 = {0.f, 0.f, 0.f, 0.f};

    // stage geometry: thread moves 4x16B blocks; swizzled dest unit = u32 ^ (row&7)
    const f16* gsb = hx + (size_t)rowg * U_ + (size_t)u32 * 8; // +32*8*i halves
    half8* ldsdst  = (half8*)(hs + row * 1024) + (u32 ^ (row & 7));
    // read side: same permutation, per-16B-unit within the row
    const int rrow = lane & 15;
    const int rsw  = rrow & 7;
    const f16* hrow = hs + rrow * 1024 + kw * 256;
    const int rq   = lane >> 4;
    float* outrow = out + (size_t)rowg * T_ * U_ + ug;

    // xp prefetch for t=0
    const f16* xpb = xp + (size_t)rowg * G3 + ug;
    float xz = (float)xpb[0], xr = (float)xpb[(size_t)U_], xh = (float)xpb[(size_t)2 * U_];

    int rb = 0, wb = 1;                 // read/write buffer indices (mod 3)

#pragma unroll 1
    for (int t = 0; t < T_; ++t) {
        // ---- 0. out store for h_{t-1}: drains under the poll ----
        if (t) outrow[(size_t)(t - 1) * U_] = h;

        // ---- 1. poll hx[rb] until every dword carries parity (t+1)&1 ----
        const unsigned pm = (unsigned)((t + 1) & 1) * 0x00010001u;
        const f16* gs = gsb + (size_t)rb * BU;
        u32x4 a0, a1, a2, a3;
        bool ok0 = false, ok1 = false, ok2 = false, ok3 = false;
        while (true) {
            if (!ok0) CLOAD(a0, gs);
            if (!ok1) CLOAD(a1, gs + 256);
            if (!ok2) CLOAD(a2, gs + 512);
            if (!ok3) CLOAD(a3, gs + 768);
            VMFENCE();   // loads feed VALU checks (register-only) -> fence + sched
            const unsigned m = 0x00010001u;
            if (!ok0) ok0 = ((((a0[0]^pm)|(a0[1]^pm)|(a0[2]^pm)|(a0[3]^pm)) & m) == 0u);
            if (!ok1) ok1 = ((((a1[0]^pm)|(a1[1]^pm)|(a1[2]^pm)|(a1[3]^pm)) & m) == 0u);
            if (!ok2) ok2 = ((((a2[0]^pm)|(a2[1]^pm)|(a2[2]^pm)|(a2[3]^pm)) & m) == 0u);
            if (!ok3) ok3 = ((((a3[0]^pm)|(a3[1]^pm)|(a3[2]^pm)|(a3[3]^pm)) & m) == 0u);
            if (__ballot(!(ok0 & ok1 & ok2 & ok3)) == 0ull) break;
        }
        ((u32x4*)ldsdst)[0]  = a0;
        ((u32x4*)ldsdst)[32] = a1;
        ((u32x4*)ldsdst)[64] = a2;
        ((u32x4*)ldsdst)[96] = a3;
        barrier_lds();

        // ---- 2. A fragments from LDS (16-lane broadcast reads, swizzled) ----
        half8 af[8];
#pragma unroll
        for (int k8 = 0; k8 < 8; ++k8)
            af[k8] = *(const half8*)(hrow + (((rq + 4 * k8) ^ rsw) << 3));

        // ---- 3. prefetch xp for t+1 ----
        int tn = (t < T_ - 1) ? t + 1 : t;
        const f16* xpn = xp + ((size_t)tn * B_ + rowg) * G3 + ug;
        float xzn = (float)xpn[0], xrn = (float)xpn[(size_t)U_], xhn = (float)xpn[(size_t)2 * U_];

        // ---- 4. MFMA ----
        f32x4 acc[3] = {z4, z4, z4};
#pragma unroll
        for (int k8 = 0; k8 < 8; ++k8)
#pragma unroll
            for (int g = 0; g < 3; ++g)
                acc[g] = __builtin_amdgcn_mfma_f32_16x16x32_f16(af[k8], bw[g][k8], acc[g], 0, 0, 0);

        // ---- 5. K-reduce via LDS (stride-5 lattice, ~conflict-free) ----
#pragma unroll
        for (int g = 0; g < 3; ++g)
#pragma unroll
            for (int e = 0; e < 4; ++e)
                red[wave][g][lane][e] = acc[g][e];
        barrier_lds();

        float sz = 0.f, sr = 0.f, sh = 0.f;
#pragma unroll
        for (int k2 = 0; k2 < 4; ++k2) {
            int w2 = uwq * 4 + k2;
            sz += red[w2][0][lsrc][ei];
            sr += red[w2][1][lsrc][ei];
            sh += red[w2][2][lsrc][ei];
        }

        // ---- 6. epilogue ----
        float zg = 1.f / (1.f + expf(-(xz + sz + bz)));
        float rg = 1.f / (1.f + expf(-(xr + sr + br)));
        float hh = tanhf(xh + rg * (sh + bh));
        h = zg * h + (1.f - zg) * hh;

        // ---- 7. publish h_t -> hx[wb], LSB = t&1 (generation tag); no sync ----
        f16 hf = (f16)h;
        unsigned my = ((unsigned)*(unsigned short*)&hf & 0xFFFEu) | (unsigned)(t & 1);
        unsigned nb = __shfl_down(my, 1);
        if ((u32 & 1) == 0) {
            unsigned* dst = (unsigned*)(hx + (size_t)wb * BU
                                        + (size_t)rowg * U_ + ug);
            __hip_atomic_store(dst, my | (nb << 16),
                               __ATOMIC_RELAXED, __HIP_MEMORY_SCOPE_AGENT);
        }

        rb = wb; wb = (wb + 1 == 3) ? 0 : wb + 1;
        xz = xzn; xr = xrn; xh = xhn;
    }
    outrow[(size_t)(T_ - 1) * U_] = h;
    out[(size_t)B_ * T_ * U_ + (size_t)rowg * U_ + ug] = h;
}

// ---------------- host ----------------
extern "C" void kernel_launch(void* const* d_in, const int* in_sizes, int n_in,
                              void* d_out, int out_size, void* d_ws, size_t ws_size,
                              hipStream_t stream) {
    const int*   x    = (const int*)d_in[0];
    const float* h0   = (const float*)d_in[1];
    const float* emb  = (const float*)d_in[2];
    const float* w1   = (const float*)d_in[3];
    const float* w2   = (const float*)d_in[4];
    const float* bias = (const float*)d_in[5];
    float* out = (float*)d_out;
    char*  ws  = (char*)d_ws;

    f16*      xe   = (f16*)(ws + OFF_XE);
    f16*      w1t  = (f16*)(ws + OFF_W1T);
    f16*      w2f  = (f16*)(ws + OFF_W2F);
    f16*      xp   = (f16*)(ws + OFF_XP);
    f16*      hx   = (f16*)(ws + OFF_HX);     // hx[3], time-shared with xe

    k_gather<<<B_ * T_ / 4, 256, 0, stream>>>(x, emb, xe);
    k_w1t<<<G3, EP, 0, stream>>>(w1, w1t);
    k_w2f<<<(192 * 32 * 64) / 256, 256, 0, stream>>>(w2, w2f);
    k_xp<<<dim3(G3 / 128, B_ * T_ / 128), 256, 0, stream>>>(xe, w1t, bias, xp);

    // xe region is dead now; hx[3] lives inside it.
    // Buffer 0: h0 with parity-1 LSBs (k_hinit). Buffers 1/2: wrong-parity
    // sentinels so the first polls can't accept garbage:
    //   buf1 read at t=1 expects LSB=0 -> fill 0xFF (LSB=1)
    //   buf2 read at t=2 expects LSB=1 -> fill 0x00 (LSB=0)
    hipMemsetAsync(ws + OFF_HX + 1ull * BUB, 0xFF, BUB, stream);
    hipMemsetAsync(ws + OFF_HX + 2ull * BUB, 0x00, BUB, stream);
    k_hinit<<<(B_ * U_ / 2) / 256, 256, 0, stream>>>(h0, hx);

    const f16*   xp_c   = xp;
    const f16*   w2f_c  = w2f;
    const float* bias1  = bias + G3;
    void* args[] = {(void*)&xp_c, (void*)&w2f_c, (void*)&bias1, (void*)&h0,
                    (void*)&hx, (void*)&out};
    if (hipLaunchCooperativeKernel((const void*)k_rec, dim3(128), dim3(512),
                                   args, 0, stream) != hipSuccess) {
        k_rec<<<128, 512, 0, stream>>>(xp_c, w2f_c, bias1, h0, hx, out);
    }
}

// Round 6
// 1311.475 us; speedup vs baseline: 1.6848x; 1.0591x over previous
//
#include <hip/hip_runtime.h>

typedef _Float16 f16;
typedef _Float16 half8 __attribute__((ext_vector_type(8)));
typedef float f32x4 __attribute__((ext_vector_type(4)));
typedef unsigned u32x4 __attribute__((ext_vector_type(4)));
typedef unsigned long long u64;

#define B_  64
#define T_  512
#define V_  32000
#define E_  300
#define EP  320      // E padded to multiple of 32 for MFMA K
#define U_  1024
#define G3  3072     // 3*U
#define BU  (B_ * U_)            // one h buffer, elements
#define BUB (B_ * U_ * 2)        // one h buffer, bytes (128 KB)

// ---- workspace layout (bytes) ----
// XE region is time-shared: k_gather/k_xp use it first, then hx lives in it.
// hx[3][64][1024] fp16 = 384 KB, parity-tagged triple buffer.
#define OFF_XE   0ull
#define OFF_HX   OFF_XE
#define OFF_W1T  (OFF_XE  + (size_t)B_*T_*EP*2)       // xe fp16 [32768][320]
#define OFF_W2F  (OFF_W1T + (size_t)G3*EP*2)
#define OFF_XP   (OFF_W2F + (size_t)U_*G3*2)

__device__ __forceinline__ void barrier_lds() {
    // LDS-only dependency barrier: don't drain vmcnt (keeps prefetches alive)
    asm volatile("s_waitcnt lgkmcnt(0)\n\ts_barrier" ::: "memory");
}

// opaque 16B load: result is an asm output -> cannot be rematerialized, so
// the allocator must keep it in VGPRs for its whole live range
#define WLOAD(dst, src) \
    asm volatile("global_load_dwordx4 %0, %1, off" : "=v"(dst) : "v"(src) : "memory")
// L1/L2-bypassing 16B load (coherent at L3)
#define CLOAD(dst, src) \
    asm volatile("global_load_dwordx4 %0, %1, off sc0 sc1" : "=v"(dst) : "v"(src) : "memory")
// vmcnt drain whose protected values feed REGISTER-ONLY consumers (VALU parity
// checks / MFMA): needs sched_barrier(0) or hipcc hoists the consumer past the
// waitcnt (rule #18 — "memory" clobber doesn't order non-memory instructions).
#define VMFENCE() do {                                      \
    asm volatile("s_waitcnt vmcnt(0)" ::: "memory");        \
    __builtin_amdgcn_sched_barrier(0);                      \
} while (0)

// ---- fast transcendentals (serial epilogue path; libm tanhf/expf are
// 40-100 inst with branches — these are 2-3 ulp f32, invisible vs fp16) ----
__device__ __forceinline__ float fexp2(float x) {
    float r; asm("v_exp_f32 %0, %1" : "=v"(r) : "v"(x)); return r;
}
__device__ __forceinline__ float frcp(float x) {
    float r; asm("v_rcp_f32 %0, %1" : "=v"(r) : "v"(x)); return r;
}
__device__ __forceinline__ float fsigmoid(float x) {
    // x>>0: exp2->0, rcp(1)=1.  x<<0: exp2->inf, rcp(inf)=0.  No NaN paths.
    return frcp(1.f + fexp2(x * -1.4426950408889634f));
}
__device__ __forceinline__ float ftanh(float x) {
    // clamp keeps e finite so (1-e)*rcp(1+e) never hits inf*0 = NaN
    float e = fexp2(fminf(x * -2.8853900817779268f, 126.f));
    return (1.f - e) * frcp(1.f + e);
}

// ---------------- setup kernels ----------------

__global__ void k_gather(const int* __restrict__ x, const float* __restrict__ emb,
                         f16* __restrict__ xe) {
    int row  = blockIdx.x * 4 + (threadIdx.x >> 6);
    int lane = threadIdx.x & 63;
    int tok  = x[row];
    const float* er = emb + (size_t)tok * E_;
    f16* xr = xe + (size_t)row * EP;
#pragma unroll
    for (int e = lane; e < EP; e += 64) {
        float v = (e < E_) ? er[e] : 0.f;
        xr[e] = (f16)v;
    }
}

__global__ void k_w1t(const float* __restrict__ w1, f16* __restrict__ w1t) {
    int n = blockIdx.x;
    int k = threadIdx.x;
    float v = (k < E_) ? w1[(size_t)k * G3 + n] : 0.f;
    w1t[(size_t)n * EP + k] = (f16)v;
}

__global__ void k_w2f(const float* __restrict__ w2, f16* __restrict__ w2f) {
    int g    = blockIdx.x * 256 + threadIdx.x;
    int lane = g & 63;
    int kt   = (g >> 6) & 31;
    int nt   = g >> 11;
    int krow = kt * 32 + (lane >> 4) * 8;
    int n    = nt * 16 + (lane & 15);
    f16* dst = w2f + ((size_t)(nt * 32 + kt) * 64 + lane) * 8;
#pragma unroll
    for (int j = 0; j < 8; ++j)
        dst[j] = (f16)w2[(size_t)(krow + j) * G3 + n];
}

// h0 fp32 -> hx[0] fp16 with LSB forced to parity 1 (generation tag for t=0),
// published at agent scope. h0 is all-zeros; LSB=1 makes it the smallest
// subnormal (~6e-8) — negligible.
__global__ void k_hinit(const float* __restrict__ h0, f16* __restrict__ hx) {
    int i = blockIdx.x * 256 + threadIdx.x;        // dword pairs
    f16 a = (f16)h0[2 * i], b = (f16)h0[2 * i + 1];
    unsigned lo = (*(unsigned short*)&a) | 1u, hi = (*(unsigned short*)&b) | 1u;
    __hip_atomic_store((unsigned*)hx + i, lo | (hi << 16),
                       __ATOMIC_RELAXED, __HIP_MEMORY_SCOPE_AGENT);
}

// ---------------- input projection GEMM ----------------
__global__ __launch_bounds__(256) void k_xp(const f16* __restrict__ xe,
                                            const f16* __restrict__ w1t,
                                            const float* __restrict__ bias0,
                                            f16* __restrict__ xp) {
    __shared__ __align__(16) f16 As[128 * 32];
    __shared__ __align__(16) f16 Bs[128 * 32];
    const int tid  = threadIdx.x;
    const int lane = tid & 63;
    const int w    = tid >> 6;
    const int wm   = w >> 1, wn = w & 1;
    const int n0   = blockIdx.x * 128;
    const int m0   = blockIdx.y * 128;

    f32x4 acc[4][4];
    const f32x4 z4 = {0.f, 0.f, 0.f, 0.f};
#pragma unroll
    for (int i = 0; i < 4; ++i)
#pragma unroll
        for (int j = 0; j < 4; ++j) acc[i][j] = z4;

    for (int kk = 0; kk < EP / 32; ++kk) {
        int k0 = kk * 32;
        __syncthreads();
#pragma unroll
        for (int c = 0; c < 2; ++c) {
            int t2 = tid + 256 * c;
            int row = t2 >> 2, kq = t2 & 3;
            ((half8*)As)[t2] = *(const half8*)(xe  + (size_t)(m0 + row) * EP + k0 + kq * 8);
            ((half8*)Bs)[t2] = *(const half8*)(w1t + (size_t)(n0 + row) * EP + k0 + kq * 8);
        }
        __syncthreads();
        half8 a[4], b[4];
#pragma unroll
        for (int i = 0; i < 4; ++i) {
            a[i] = ((half8*)As)[(wm * 64 + i * 16 + (lane & 15)) * 4 + (lane >> 4)];
            b[i] = ((half8*)Bs)[(wn * 64 + i * 16 + (lane & 15)) * 4 + (lane >> 4)];
        }
#pragma unroll
        for (int i = 0; i < 4; ++i)
#pragma unroll
            for (int j = 0; j < 4; ++j)
                acc[i][j] = __builtin_amdgcn_mfma_f32_16x16x32_f16(a[i], b[j], acc[i][j], 0, 0, 0);
    }

    float bv[4];
#pragma unroll
    for (int j = 0; j < 4; ++j) bv[j] = bias0[n0 + wn * 64 + j * 16 + (lane & 15)];
#pragma unroll
    for (int i = 0; i < 4; ++i)
#pragma unroll
        for (int j = 0; j < 4; ++j)
#pragma unroll
            for (int e = 0; e < 4; ++e) {
                int rl  = wm * 64 + i * 16 + (lane >> 4) * 4 + e;
                int bt  = m0 + rl;
                int tt  = bt & (T_ - 1);
                int bb  = bt >> 9;
                int col = n0 + wn * 64 + j * 16 + (lane & 15);
                xp[((size_t)tt * B_ + bb) * G3 + col] = (f16)(acc[i][j][e] + bv[j]);
            }
}

// ---------------- persistent GRU recurrence ----------------
// 128 blocks x 512 threads. rw = blk&3 (16 batch rows), ut2 = blk>>2 (32 u).
// SYNC-FREE h exchange: publish h_t into hx[(t+1)%3] with every fp16's LSB
// forced to parity (t&1). Consumers poll the data itself (per-16b parity
// check) — no flags, no group barrier, no publish-ack drain. Dataflow bounds
// block spread to <=1 step; with 3 buffers and odd rotation distance the
// parity uniquely identifies the wanted generation (stale/future differ).
// Publish is per-thread global_store_short (2B stores are atomic; parity is
// per-16b, so no dword pairing/shfl needed).
// out stores are issued AFTER the poll (vmcnt retires in order — a pre-poll
// HBM store ack would gate every first poll check) and are nontemporal.
// hs is XOR-swizzled at 16B granularity: physical unit = logical ^ (row&7).
// red is [..][64][5]: lane-stride 5 dwords -> reduce reads ~conflict-free.
__global__ __launch_bounds__(512, 2) void k_rec(const f16* __restrict__ xp,
                                                const f16* __restrict__ w2f,
                                                const float* __restrict__ bias1,
                                                const float* __restrict__ h0,
                                                f16* __restrict__ hx,
                                                float* __restrict__ out) {
    const int tid  = threadIdx.x;
    const int lane = tid & 63;
    const int wave = tid >> 6;          // 0..7
    const int uw   = wave >> 2;         // 0..1
    const int kw   = wave & 3;          // 0..3
    const int rw   = blockIdx.x & 3;
    const int ut2  = blockIdx.x >> 2;   // 0..31
    const int ut16 = ut2 * 2 + uw;      // 16-u tile id 0..63

    __shared__ __align__(16) f16   hs[16 * 1024];       // 32 KB staged h (swizzled)
    __shared__ __align__(16) float red[8][3][64][5];    // 30 KB K-partials (stride-5)

    // resident weights: opaque asm loads -> pinned in VGPRs
    half8 bw[3][8];
#pragma unroll
    for (int g = 0; g < 3; ++g) {
        int nt = g * 64 + ut16;
#pragma unroll
        for (int k8 = 0; k8 < 8; ++k8) {
            int kt = kw * 8 + k8;
            const f16* src = w2f + ((size_t)(nt * 32 + kt) * 64 + lane) * 8;
            WLOAD(bw[g][k8], src);
        }
    }
    VMFENCE();

    const int row  = tid >> 5;          // 0..15
    const int u32  = tid & 31;          // 0..31
    const int rowg = rw * 16 + row;     // global batch row
    const int ug   = ut2 * 32 + u32;    // hidden unit
    float h = h0[rowg * U_ + ug];       // fp32 state in register
    const float bz = bias1[ug], br = bias1[U_ + ug], bh = bias1[2 * U_ + ug];
    const int lsrc = (row >> 2) * 16 + (u32 & 15);
    const int ei   = row & 3;
    const int uwq  = u32 >> 4;
    const f32x4 z4 = {0.f, 0.f, 0.f, 0.f};

    // stage geometry: thread moves 4x16B blocks; swizzled dest unit = u32 ^ (row&7)
    const f16* gsb = hx + (size_t)rowg * U_ + (size_t)u32 * 8; // +32*8*i halves
    half8* ldsdst  = (half8*)(hs + row * 1024) + (u32 ^ (row & 7));
    // read side: same permutation, per-16B-unit within the row
    const int rrow = lane & 15;
    const int rsw  = rrow & 7;
    const f16* hrow = hs + rrow * 1024 + kw * 256;
    const int rq   = lane >> 4;
    float* outrow = out + (size_t)rowg * T_ * U_ + ug;
    f16* pubbase = hx + (size_t)rowg * U_ + ug;

    // xp prefetch for t=0
    const f16* xpb = xp + (size_t)rowg * G3 + ug;
    float xz = (float)xpb[0], xr = (float)xpb[(size_t)U_], xh = (float)xpb[(size_t)2 * U_];

    int rb = 0, wb = 1;                 // read/write buffer indices (mod 3)

#pragma unroll 1
    for (int t = 0; t < T_; ++t) {
        // ---- 1. poll hx[rb] until every 16b lane carries parity (t+1)&1 ----
        const unsigned pm = (unsigned)((t + 1) & 1) * 0x00010001u;
        const f16* gs = gsb + (size_t)rb * BU;
        u32x4 a0, a1, a2, a3;
        bool ok0 = false, ok1 = false, ok2 = false, ok3 = false;
        while (true) {
            if (!ok0) CLOAD(a0, gs);
            if (!ok1) CLOAD(a1, gs + 256);
            if (!ok2) CLOAD(a2, gs + 512);
            if (!ok3) CLOAD(a3, gs + 768);
            VMFENCE();   // loads feed VALU checks (register-only) -> fence + sched
            const unsigned m = 0x00010001u;
            if (!ok0) ok0 = ((((a0[0]^pm)|(a0[1]^pm)|(a0[2]^pm)|(a0[3]^pm)) & m) == 0u);
            if (!ok1) ok1 = ((((a1[0]^pm)|(a1[1]^pm)|(a1[2]^pm)|(a1[3]^pm)) & m) == 0u);
            if (!ok2) ok2 = ((((a2[0]^pm)|(a2[1]^pm)|(a2[2]^pm)|(a2[3]^pm)) & m) == 0u);
            if (!ok3) ok3 = ((((a3[0]^pm)|(a3[1]^pm)|(a3[2]^pm)|(a3[3]^pm)) & m) == 0u);
            if (__ballot(!(ok0 & ok1 & ok2 & ok3)) == 0ull) break;
        }
        ((u32x4*)ldsdst)[0]  = a0;
        ((u32x4*)ldsdst)[32] = a1;
        ((u32x4*)ldsdst)[64] = a2;
        ((u32x4*)ldsdst)[96] = a3;
        // ---- 2. out store for h_{t-1}: after the poll (in-order vmcnt would
        //         gate the poll on its HBM ack); nt = don't pollute L2 ----
        if (t) __builtin_nontemporal_store(h, outrow + (size_t)(t - 1) * U_);
        barrier_lds();

        // ---- 3. A fragments from LDS (16-lane broadcast reads, swizzled) ----
        half8 af[8];
#pragma unroll
        for (int k8 = 0; k8 < 8; ++k8)
            af[k8] = *(const half8*)(hrow + (((rq + 4 * k8) ^ rsw) << 3));

        // ---- 4. prefetch xp for t+1 ----
        int tn = (t < T_ - 1) ? t + 1 : t;
        const f16* xpn = xp + ((size_t)tn * B_ + rowg) * G3 + ug;
        float xzn = (float)xpn[0], xrn = (float)xpn[(size_t)U_], xhn = (float)xpn[(size_t)2 * U_];

        // ---- 5. MFMA ----
        f32x4 acc[3] = {z4, z4, z4};
#pragma unroll
        for (int k8 = 0; k8 < 8; ++k8)
#pragma unroll
            for (int g = 0; g < 3; ++g)
                acc[g] = __builtin_amdgcn_mfma_f32_16x16x32_f16(af[k8], bw[g][k8], acc[g], 0, 0, 0);

        // ---- 6. K-reduce via LDS (stride-5 lattice, ~conflict-free) ----
#pragma unroll
        for (int g = 0; g < 3; ++g)
#pragma unroll
            for (int e = 0; e < 4; ++e)
                red[wave][g][lane][e] = acc[g][e];
        barrier_lds();

        float sz = 0.f, sr = 0.f, sh = 0.f;
#pragma unroll
        for (int k2 = 0; k2 < 4; ++k2) {
            int w2 = uwq * 4 + k2;
            sz += red[w2][0][lsrc][ei];
            sr += red[w2][1][lsrc][ei];
            sh += red[w2][2][lsrc][ei];
        }

        // ---- 7. epilogue (fast transcendentals; fully serial path) ----
        float zg = fsigmoid(xz + sz + bz);
        float rg = fsigmoid(xr + sr + br);
        float hh = ftanh(xh + rg * (sh + bh));
        h = zg * h + (1.f - zg) * hh;

        // ---- 8. publish h_t -> hx[wb], LSB = t&1; 2B store, no pairing ----
        f16 hf = (f16)h;
        unsigned my = ((unsigned)*(unsigned short*)&hf & 0xFFFEu) | (unsigned)(t & 1);
        const f16* dst = pubbase + (size_t)wb * BU;
        asm volatile("global_store_short %0, %1, off sc0 sc1"
                     :: "v"(dst), "v"(my) : "memory");

        rb = wb; wb = (wb + 1 == 3) ? 0 : wb + 1;
        xz = xzn; xr = xrn; xh = xhn;
    }
    __builtin_nontemporal_store(h, outrow + (size_t)(T_ - 1) * U_);
    __builtin_nontemporal_store(h, out + (size_t)B_ * T_ * U_ + (size_t)rowg * U_ + ug);
}

// ---------------- host ----------------
extern "C" void kernel_launch(void* const* d_in, const int* in_sizes, int n_in,
                              void* d_out, int out_size, void* d_ws, size_t ws_size,
                              hipStream_t stream) {
    const int*   x    = (const int*)d_in[0];
    const float* h0   = (const float*)d_in[1];
    const float* emb  = (const float*)d_in[2];
    const float* w1   = (const float*)d_in[3];
    const float* w2   = (const float*)d_in[4];
    const float* bias = (const float*)d_in[5];
    float* out = (float*)d_out;
    char*  ws  = (char*)d_ws;

    f16*      xe   = (f16*)(ws + OFF_XE);
    f16*      w1t  = (f16*)(ws + OFF_W1T);
    f16*      w2f  = (f16*)(ws + OFF_W2F);
    f16*      xp   = (f16*)(ws + OFF_XP);
    f16*      hx   = (f16*)(ws + OFF_HX);     // hx[3], time-shared with xe

    k_gather<<<B_ * T_ / 4, 256, 0, stream>>>(x, emb, xe);
    k_w1t<<<G3, EP, 0, stream>>>(w1, w1t);
    k_w2f<<<(192 * 32 * 64) / 256, 256, 0, stream>>>(w2, w2f);
    k_xp<<<dim3(G3 / 128, B_ * T_ / 128), 256, 0, stream>>>(xe, w1t, bias, xp);

    // xe region is dead now; hx[3] lives inside it.
    // Buffer 0: h0 with parity-1 LSBs (k_hinit). Buffers 1/2: wrong-parity
    // sentinels so the first polls can't accept garbage:
    //   buf1 read at t=1 expects LSB=0 -> fill 0xFF (LSB=1)
    //   buf2 read at t=2 expects LSB=1 -> fill 0x00 (LSB=0)
    hipMemsetAsync(ws + OFF_HX + 1ull * BUB, 0xFF, BUB, stream);
    hipMemsetAsync(ws + OFF_HX + 2ull * BUB, 0x00, BUB, stream);
    k_hinit<<<(B_ * U_ / 2) / 256, 256, 0, stream>>>(h0, hx);

    const f16*   xp_c   = xp;
    const f16*   w2f_c  = w2f;
    const float* bias1  = bias + G3;
    void* args[] = {(void*)&xp_c, (void*)&w2f_c, (void*)&bias1, (void*)&h0,
                    (void*)&hx, (void*)&out};
    if (hipLaunchCooperativeKernel((const void*)k_rec, dim3(128), dim3(512),
                                   args, 0, stream) != hipSuccess) {
        k_rec<<<128, 512, 0, stream>>>(xp_c, w2f_c, bias1, h0, hx, out);
    }
}